// Round 10
// baseline (285.734 us; speedup 1.0000x reference)
//
#include <hip/hip_runtime.h>

typedef unsigned long long u64;
typedef unsigned int u32;

#define R_TOT 159882
#define POST 1000
#define IMG_SZ 800.0f
#define NMS_TH 0.7f
#define BBOX_CLIP 4.135166556742356f
#define LCAP 1024

__device__ __forceinline__ float fadd_(float a, float b){ return __fadd_rn(a,b); }
__device__ __forceinline__ float fsub_(float a, float b){ return __fsub_rn(a,b); }
__device__ __forceinline__ float fmul_(float a, float b){ return __fmul_rn(a,b); }

__device__ __forceinline__ int lvl_len(int l){ const int L[5]={120000,30000,7500,1875,507}; return L[l]; }
__device__ __forceinline__ int lvl_off(int l){ const int L[5]={0,120000,150000,157500,159375}; return L[l]; }
__device__ __forceinline__ int lvl_k(int l){ const int L[5]={1000,1000,1000,1000,507}; return L[l]; }

__device__ __forceinline__ u32 mono_(u32 u){ return (u & 0x80000000u) ? ~u : (u | 0x80000000u); }

__device__ __forceinline__ u64 readlane64(u64 v, int i){
  u32 lo = (u32)__builtin_amdgcn_readlane((int)(u32)v, i);
  u32 hi = (u32)__builtin_amdgcn_readlane((int)(u32)(v >> 32), i);
  return ((u64)hi << 32) | (u64)lo;
}

// ---------- 1. per-slice 12-bit histogram: LDS-private, overwrite (no memset needed) ----------
__global__ __launch_bounds__(256) void k_hist(const float* __restrict__ obj, int* hist16){
  int g = blockIdx.x, sl = blockIdx.y;
  int img = g/5, lvl = g%5;
  int n = lvl_len(lvl), s0 = lvl_off(lvl);
  __shared__ int lh[4096];
  int tid = threadIdx.x;
  for (int i = tid; i < 4096; i += 256) lh[i] = 0;
  __syncthreads();
  int lo = (int)((long long)n * sl / 16), hiS = (int)((long long)n * (sl+1) / 16);
  const float* p = obj + img*R_TOT + s0;
  #pragma unroll 4
  for (int e = lo + tid; e < hiS; e += 256){
    u32 mu = mono_(__float_as_uint(p[e]));
    atomicAdd(&lh[(~mu) >> 20], 1);
  }
  __syncthreads();
  int* dst = hist16 + (g*16 + sl)*4096;
  for (int i = tid; i < 4096; i += 256) dst[i] = lh[i];   // full overwrite
}

// ---------- 2. sum slices + pick the k-th bin; zero collect counters ----------
__global__ __launch_bounds__(1024) void k_pick(const int* __restrict__ hist16,
                                               int* bstarG, int* remG, int* cntg, int* cnt2){
  int g = blockIdx.x, lvl = g % 5, k = lvl_k(lvl);
  int tid = threadIdx.x, lane = tid & 63, wid = tid >> 6;
  __shared__ int wsum[16];
  const int* hb = hist16 + g*16*4096;
  int hh[4] = {0,0,0,0};
  #pragma unroll
  for (int sl = 0; sl < 16; sl++){
    const int* hs = hb + sl*4096 + 4*tid;
    hh[0] += hs[0]; hh[1] += hs[1]; hh[2] += hs[2]; hh[3] += hs[3];
  }
  int part = hh[0] + hh[1] + hh[2] + hh[3];
  int x = part;
  for (int d = 1; d < 64; d <<= 1){ int y = __shfl_up(x, d); if (lane >= d) x += y; }
  if (lane == 63) wsum[wid] = x;
  __syncthreads();
  int add = 0;
  for (int w = 0; w < wid; w++) add += wsum[w];
  int incl = x + add, excl = incl - part;
  if (excl < k && k <= incl){
    int cum = excl;
    #pragma unroll
    for (int q = 0; q < 4; q++){
      if (cum + hh[q] >= k){ bstarG[g] = 4*tid + q; remG[g] = k - cum; break; }
      cum += hh[q];
    }
  }
  if (tid == 0){ cntg[g] = 0; cnt2[g] = 0; }
}

// ---------- 3. wide collect scan: bin<b* -> mainG, bin==b* -> LbufG ----------
__global__ __launch_bounds__(256) void k_collect(const float* __restrict__ obj,
                                                 const int* __restrict__ bstarG,
                                                 int* cntg, int* cnt2,
                                                 u64* mainG, u64* LbufG){
  int g = blockIdx.x, sl = blockIdx.y;
  int img = g/5, lvl = g%5;
  int n = lvl_len(lvl), s0 = lvl_off(lvl);
  int lo = (int)((long long)n * sl / 16), hiS = (int)((long long)n * (sl+1) / 16);
  const float* p = obj + img*R_TOT + s0;
  int bs = bstarG[g];
  #pragma unroll 8
  for (int e = lo + threadIdx.x; e < hiS; e += 256){
    u32 mu = mono_(__float_as_uint(p[e]));
    u64 key56 = (((u64)(~mu)) << 24) | (u32)(s0 + e);
    int bin = (int)(key56 >> 44);
    if (bin < bs){ int pos = atomicAdd(&cntg[g], 1); mainG[g*1024 + pos] = key56; }
    else if (bin == bs){ int pos = atomicAdd(&cnt2[g], 1); if (pos < LCAP) LbufG[g*LCAP + pos] = key56; }
  }
}

// ---------- 4. fused: tie-resolve + sort + decode + compaction + in-LDS NMS ----------
__global__ __launch_bounds__(1024) void k_megasel(const float* __restrict__ obj,
                                                  const float4* __restrict__ deltas,
                                                  const float4* __restrict__ anchors,
                                                  const u64* __restrict__ mainG,
                                                  const u64* __restrict__ LbufG,
                                                  const int* __restrict__ cntg,
                                                  const int* __restrict__ cnt2,
                                                  const int* __restrict__ remG,
                                                  const int* __restrict__ bstarG,
                                                  float4* boxL, float* scoreL,
                                                  u64* okeyN, u64* keptW, int* ncnt){
  int g = blockIdx.x, img = g/5, lvl = g%5;
  int s0 = lvl_off(lvl), n = lvl_len(lvl), k = lvl_k(lvl);
  const float* p = obj + img*R_TOT + s0;
  // bufA: phase1 = Lbuf/lokey (lo 1024) + mainL (hi 1024); phase3 = keptbox (float4[1024])
  __shared__ u64 bufA[2048];
  __shared__ float4 lbox[1024];
  __shared__ float4 nboxL[1024];
  __shared__ u64 fwdPart[16*64];
  __shared__ u64 suppw[16];
  __shared__ u64 validW[16];
  __shared__ int h16s[16];
  __shared__ int sh_sc, sh_rem, sh_m, sh_K;
  __shared__ u64 sh_thr;
  u64* Lbuf = bufA;
  u64* lokey = bufA;             // reuses Lbuf region (dead after tie-resolve)
  u64* mainL = bufA + 1024;
  float4* keptbox = (float4*)bufA; // reuses whole bufA (dead after compaction)
  int tid = threadIdx.x, lane = tid & 63, wid = tid >> 6;
  int nb = cntg[g];
  int c2 = cnt2[g];
  int rem = remG[g];
  int bs = bstarG[g];
  mainL[tid] = (tid < nb) ? mainG[g*1024 + tid] : ~0ull;
  if (tid == 0){ sh_sc = 0; sh_rem = rem; }
  int c2c = c2 < LCAP ? c2 : LCAP;
  if (tid < c2c) Lbuf[tid] = LbufG[g*LCAP + tid];
  __syncthreads();
  if (c2 <= LCAP){
    // rank-select within the tie bin (order-independent, LDS broadcast)
    if (tid < c2){
      u64 kk = Lbuf[tid];
      int rk = 0;
      for (int q = 0; q < c2; q++) rk += (Lbuf[q] < kk) ? 1 : 0;
      if (rk < rem){ int p2 = atomicAdd(&sh_sc, 1); mainL[nb + p2] = kk; }
    }
  } else {
    // fallback: 4-bit radix refine over global (never hit on bench data)
    if (tid == 0) sh_thr = ((u64)bs) << 44;
    __syncthreads();
    for (int shift = 40; shift >= 0; shift -= 4){
      if (tid < 16) h16s[tid] = 0;
      __syncthreads();
      u64 pref = sh_thr;
      u64 himask = ~((1ull << (shift+4)) - 1ull);
      for (int e = tid; e < n; e += 1024){
        u32 mu = mono_(__float_as_uint(p[e]));
        u64 kk = (((u64)(~mu)) << 24) | (u32)(s0 + e);
        if ((kk & himask) == (pref & himask)) atomicAdd(&h16s[(int)((kk >> shift) & 15)], 1);
      }
      __syncthreads();
      if (tid == 0){
        int r2 = sh_rem, cum = 0;
        for (int d = 0; d < 16; d++){
          int hb2 = h16s[d];
          if (cum + hb2 >= r2){ sh_thr = pref | ((u64)d << shift); sh_rem = r2 - cum; break; }
          cum += hb2;
        }
      }
      __syncthreads();
    }
    u64 thr = sh_thr;
    for (int e = tid; e < n; e += 1024){
      u32 mu = mono_(__float_as_uint(p[e]));
      u64 kk = (((u64)(~mu)) << 24) | (u32)(s0 + e);
      if ((int)(kk >> 44) == bs && kk <= thr){ int p2 = atomicAdd(&sh_sc, 1); mainL[nb + p2] = kk; }
    }
  }
  __syncthreads();
  // --- bitonic sort 1024 ---
  for (int k2 = 2; k2 <= 1024; k2 <<= 1){
    for (int j = k2 >> 1; j > 0; j >>= 1){
      __syncthreads();
      int i = tid, ixj = i ^ j;
      if (ixj > i){
        u64 a = mainL[i], b = mainL[ixj];
        bool up = (i & k2) == 0;
        if ((a > b) == up){ mainL[i] = b; mainL[ixj] = a; }
      }
    }
  }
  __syncthreads();
  // --- decode + clip + valid + sigmoid + okey ---
  int r = tid, t = g*1024 + r;
  bool validF = false;
  if (r < k){
    int idx = (int)(mainL[r] & 0xFFFFFFu);
    float4 a = anchors[idx];
    float4 d = deltas[img*R_TOT + idx];
    float o = obj[img*R_TOT + idx];
    float wa = fsub_(a.z, a.x), ha = fsub_(a.w, a.y);
    float cxa = fadd_(a.x, fmul_(0.5f, wa)), cya = fadd_(a.y, fmul_(0.5f, ha));
    float dw = fminf(d.z, BBOX_CLIP), dh = fminf(d.w, BBOX_CLIP);
    float cx = fadd_(fmul_(d.x, wa), cxa), cy = fadd_(fmul_(d.y, ha), cya);
    float w  = fmul_(expf(dw), wa),        h  = fmul_(expf(dh), ha);
    float x1 = fsub_(cx, fmul_(0.5f, w)), y1 = fsub_(cy, fmul_(0.5f, h));
    float x2 = fadd_(cx, fmul_(0.5f, w)), y2 = fadd_(cy, fmul_(0.5f, h));
    x1 = fminf(fmaxf(x1, 0.0f), IMG_SZ); y1 = fminf(fmaxf(y1, 0.0f), IMG_SZ);
    x2 = fminf(fmaxf(x2, 0.0f), IMG_SZ); y2 = fminf(fmaxf(y2, 0.0f), IMG_SZ);
    validF = (fsub_(x2, x1) >= 1e-3f) && (fsub_(y2, y1) >= 1e-3f);
    float e = expf(-o);
    float sig = __fdiv_rn(1.0f, fadd_(1.0f, e));
    float s = validF ? sig : -1.0f;
    u32 sb = __float_as_uint(s);
    u32 ms = (sb & 0x80000000u) ? ~sb : (sb | 0x80000000u);
    float4 b4 = make_float4(x1, y1, x2, y2);
    boxL[t] = b4;
    scoreL[t] = sig;
    lokey[r] = (((u64)(~ms)) << 32) | (u32)(lvl*1000 + r);
    lbox[r] = b4;
  }
  validW[wid] = __ballot(validF);
  __syncthreads();
  // --- valid-compaction (wave 0): nboxL (+801*lvl offset, LDS) and okeyN (global) ---
  if (wid == 0){
    int cnt = 0;
    float off = (float)lvl * 801.0f;
    #pragma unroll
    for (int w = 0; w < 16; w++){
      u64 mask = validW[w];
      int r2 = w*64 + lane;
      bool v = (mask >> lane) & 1ull;
      int before = __popcll(mask & ((1ull << lane) - 1ull));
      if (v){
        int pos = cnt + before;
        float4 b = lbox[r2];
        nboxL[pos] = make_float4(fadd_(b.x,off), fadd_(b.y,off), fadd_(b.z,off), fadd_(b.w,off));
        okeyN[g*1024 + pos] = lokey[r2];
      }
      cnt += __popcll(mask);
    }
    if (lane == 0){ ncnt[g] = cnt; sh_m = cnt; sh_K = 0; }
  }
  __syncthreads();
  // --- in-LDS NMS: supp vs kept list + diag forward words + scalar ffs chain ---
  int m = sh_m;
  int nch = (m + 63) >> 6;
  for (int c = 0; c < nch; c++){
    int j = c*64 + lane;
    bool inr = j < m;
    float4 mb = inr ? nboxL[j] : make_float4(0,0,0,0);
    float areaJ = fmul_(fsub_(mb.z,mb.x), fsub_(mb.w,mb.y));
    int K = sh_K;
    // supp: row j (later) vs kept boxes (earlier) — same operand roles as R9 off-diag tiles
    bool found = false;
    for (int i = wid; i < K; i += 16){
      float4 kb = keptbox[i];
      float ltx = fmaxf(mb.x, kb.x), lty = fmaxf(mb.y, kb.y);
      float rbx = fminf(mb.z, kb.z), rby = fminf(mb.w, kb.w);
      float wx = fmaxf(fsub_(rbx, ltx), 0.0f), wy = fmaxf(fsub_(rby, lty), 0.0f);
      float inter = fmul_(wx, wy);
      float areaB = fmul_(fsub_(kb.z,kb.x), fsub_(kb.w,kb.y));
      float den = fadd_(fsub_(fadd_(areaJ, areaB), inter), 1e-9f);
      if (inr && (__fdiv_rn(inter, den) > NMS_TH)) found = true;
    }
    suppw[wid] = __ballot(found);
    // diag: row lane (earlier) vs jp>lane (later) — same operand roles as R9 diagonal
    int imax = m - c*64; if (imax > 64) imax = 64;
    u64 fp = 0;
    #pragma unroll
    for (int q = 0; q < 4; q++){
      int jp = wid*4 + q;
      if (jp > lane && jp < imax){
        float4 pb = nboxL[c*64 + jp];
        float ltx = fmaxf(mb.x, pb.x), lty = fmaxf(mb.y, pb.y);
        float rbx = fminf(mb.z, pb.z), rby = fminf(mb.w, pb.w);
        float wx = fmaxf(fsub_(rbx, ltx), 0.0f), wy = fmaxf(fsub_(rby, lty), 0.0f);
        float inter = fmul_(wx, wy);
        float areaB = fmul_(fsub_(pb.z,pb.x), fsub_(pb.w,pb.y));
        float den = fadd_(fsub_(fadd_(areaJ, areaB), inter), 1e-9f);
        if (__fdiv_rn(inter, den) > NMS_TH) fp |= (1ull << jp);
      }
    }
    fwdPart[wid*64 + lane] = fp;
    __syncthreads();
    if (wid == 0){
      u64 S = 0, fwdreg = 0;
      #pragma unroll
      for (int w = 0; w < 16; w++){ S |= suppw[w]; fwdreg |= fwdPart[w*64 + lane]; }
      u64 rowmask = (imax >= 64) ? ~0ull : ((1ull << imax) - 1ull);
      u64 live = (~S) & rowmask;
      u64 fz = __ballot(fwdreg != 0);
      u64 kept = 0;
      while (live){
        if (!(live & fz)){ kept |= live; break; }
        int i = __builtin_ctzll(live);
        kept |= (1ull << i);
        live &= ~(1ull << i);
        live &= ~readlane64(fwdreg, i);
      }
      if (lane == 0) keptW[g*16 + c] = kept;
      if ((kept >> lane) & 1ull){
        int pos = K + __popcll(kept & ((1ull << lane) - 1ull));
        keptbox[pos] = mb;
      }
      if (lane == 0) sh_K = K + __popcll(kept);
    }
    __syncthreads();
  }
}

__device__ __forceinline__ int lbound(const u64* a, int n, u64 key){
  int lo = 0, hi = n;
  while (lo < hi){ int mid = (lo + hi) >> 1; if (a[mid] < key) lo = mid + 1; else hi = mid; }
  return lo;
}

// ---------- 5. merge: runs from keptW/okeyN, rank by binary search, scatter ----------
__global__ __launch_bounds__(1024) void k_merge(const u64* __restrict__ keptW,
                                                const u64* __restrict__ okeyN,
                                                const int* __restrict__ ncnt,
                                                const float4* __restrict__ boxL,
                                                const float* __restrict__ scoreL,
                                                float* out){
  int img = blockIdx.x, tid = threadIdx.x, lane = tid & 63, wid = tid >> 6;
  __shared__ u64 runs[5*1024];
  __shared__ int cl[5];
  if (tid < 5) cl[tid] = 0;
  __syncthreads();
  if (wid < 5){
    int l = wid, g = img*5 + l;
    int m = ncnt[g];
    int nch = (m + 63) >> 6;
    int cnt = 0;
    for (int c = 0; c < nch; c++){
      u64 w = keptW[g*16 + c];
      bool kp = (w >> lane) & 1ull;
      int before = __popcll(w & ((1ull << lane) - 1ull));
      if (kp) runs[l*1024 + cnt + before] = okeyN[g*1024 + c*64 + lane];
      cnt += __popcll(w);
    }
    if (lane == 0) cl[l] = cnt;
  }
  __syncthreads();
  for (int t = tid; t < POST; t += 1024){
    out[img*POST*4 + t*4 + 0] = 0.0f;
    out[img*POST*4 + t*4 + 1] = 0.0f;
    out[img*POST*4 + t*4 + 2] = 0.0f;
    out[img*POST*4 + t*4 + 3] = 0.0f;
    out[2*POST*4 + img*POST + t] = -1.0f;
  }
  __syncthreads();
  for (int idx = tid; idx < 5*1024; idx += 1024){
    int l = idx >> 10, i = idx & 1023;
    if (i < cl[l]){
      u64 key = runs[l*1024 + i];
      int rank = i;
      #pragma unroll
      for (int l2 = 0; l2 < 5; l2++)
        if (l2 != l) rank += lbound(runs + l2*1024, cl[l2], key);
      if (rank < POST){
        int pos = (int)(key & 0xFFFFFFFFull);
        int lvl = pos / 1000, r = pos - lvl*1000;
        int gg = img*5 + lvl;
        float4 bo = boxL[gg*1024 + r];
        float sc = scoreL[gg*1024 + r];
        out[img*POST*4 + rank*4 + 0] = bo.x;
        out[img*POST*4 + rank*4 + 1] = bo.y;
        out[img*POST*4 + rank*4 + 2] = bo.z;
        out[img*POST*4 + rank*4 + 3] = bo.w;
        out[2*POST*4 + img*POST + rank] = sc;
      }
    }
  }
}

extern "C" void kernel_launch(void* const* d_in, const int* in_sizes, int n_in,
                              void* d_out, int out_size, void* d_ws, size_t ws_size,
                              hipStream_t stream){
  (void)in_sizes; (void)n_in; (void)out_size; (void)ws_size;
  const float*  obj     = (const float*)d_in[0];
  const float4* deltas  = (const float4*)d_in[1];
  const float4* anchors = (const float4*)d_in[2];
  float* out = (float*)d_out;
  char* ws = (char*)d_ws;
  int* hist16  = (int*)(ws + 0);           // 10*16*4096 int -> 2621440
  int* bstarG  = (int*)(ws + 2621440);     //                -> 2621696
  int* remG    = (int*)(ws + 2621696);     //                -> 2621952
  int* cntg    = (int*)(ws + 2621952);     //                -> 2622208
  int* cnt2    = (int*)(ws + 2622208);     //                -> 2622464
  u64* mainG   = (u64*)(ws + 2622464);     // 10*1024 u64    -> 2704384
  u64* LbufG   = (u64*)(ws + 2704384);     // 10*1024 u64    -> 2786304
  float4* boxL = (float4*)(ws + 2786304);  // 10*1024 f4     -> 2950144
  float* scoreL= (float*)(ws + 2950144);   // 10*1024 f32    -> 2991104
  u64* okeyN   = (u64*)(ws + 2991104);     // 10*1024 u64    -> 3073024
  u64* keptW   = (u64*)(ws + 3073024);     // 10*16 u64      -> 3074304
  int* ncnt    = (int*)(ws + 3074304);     // 10 int (pad)   -> 3074560

  {
    dim3 gh(10, 16);
    k_hist<<<gh, 256, 0, stream>>>(obj, hist16);
  }
  k_pick<<<10, 1024, 0, stream>>>(hist16, bstarG, remG, cntg, cnt2);
  {
    dim3 gc(10, 16);
    k_collect<<<gc, 256, 0, stream>>>(obj, bstarG, cntg, cnt2, mainG, LbufG);
  }
  k_megasel<<<10, 1024, 0, stream>>>(obj, deltas, anchors, mainG, LbufG, cntg, cnt2,
                                     remG, bstarG, boxL, scoreL, okeyN, keptW, ncnt);
  k_merge<<<2, 1024, 0, stream>>>(keptW, okeyN, ncnt, boxL, scoreL, out);
}